// Round 1
// baseline (1404.670 us; speedup 1.0000x reference)
//
#include <hip/hip_runtime.h>
#include <math.h>

// Denoiser: STFT (windowed DFT as GEMM) -> spectral bias-subtract -> iSTFT
// (GEMM + overlap-add). Bases regenerated analytically on device each call.
//
// Workspace layout (floats):
//   fwd  @ 0          : 1026*1024 = 1,050,624   forward basis  [c][k]
//   invt @ 1,050,624  : 1024*1026 = 1,050,624   inverse basis^T [n][c]
//   ft   @ 2,101,248  : 4*1026*4097 = 16,814,088  spectrum / rec [b][c][f]
//   y    @ 18,915,336 : 4*4097*1024 = 16,781,312  frames [b][f][n]
// total 142,786,592 bytes

#define NFFT 1024
#define HOP  256
#define CUT  513
#define C2   1026
#define NFR  4097
#define NB   4
#define LAUD 1048576

#define TILE 64
#define TKS  16

__device__ __forceinline__ int reflect_idx(int j) {
    if (j < 0) j = -j;
    if (j >= LAUD) j = 2 * LAUD - 2 - j;
    return j;
}

__global__ void build_bases_k(float* __restrict__ fwd, float* __restrict__ invt) {
    int idx = blockIdx.x * blockDim.x + threadIdx.x;
    if (idx >= C2 * NFFT) return;
    int c = idx >> 10;       // / NFFT
    int n = idx & 1023;
    const float CST = 6.135923151542565e-3f;  // 2*pi/1024
    float win = 0.5f - 0.5f * cosf(CST * (float)n);
    int k = (c < CUT) ? c : c - CUT;
    int m = (k * n) & 1023;          // exploit DFT periodicity: exact reduction
    float si, co;
    sincosf(CST * (float)m, &si, &co);
    float base = (c < CUT) ? co : -si;
    fwd[idx] = base * win;
    float d;
    if (c < CUT) {
        d = (c == 0 || c == 512) ? (1.0f / 1024.0f) : (2.0f / 1024.0f);
    } else {
        int kk = c - CUT;
        d = (kk == 0 || kk == 512) ? 0.0f : (2.0f / 1024.0f);
    }
    invt[n * C2 + c] = 0.25f * base * d * win;
}

// C[b,c,f] = sum_k fwd[c,k] * padded_audio[b, f*HOP + k]
__global__ __launch_bounds__(256) void gemm_fwd_k(const float* __restrict__ fwd,
                                                  const float* __restrict__ audio,
                                                  float* __restrict__ ft) {
    __shared__ float As[TKS][TILE + 4];  // [kk][c_local]
    __shared__ float Bs[TKS][TILE + 4];  // [kk][f_local]
    int tid = threadIdx.x;
    int tx = tid & 15, ty = tid >> 4;
    int c0 = blockIdx.y * TILE;
    int f0 = blockIdx.x * TILE;
    int b  = blockIdx.z;
    const float* ab = audio + (long)b * LAUD;
    float acc[4][4] = {};
    int la_r = tid >> 2;        // 0..63 (row within tile)
    int la_k = (tid & 3) * 4;   // 0,4,8,12 (k within tile)

    for (int k0 = 0; k0 < NFFT; k0 += TKS) {
        // A tile: fwd[c0+la_r][k0+la_k .. +3]
        int ca = c0 + la_r;
        float4 av = make_float4(0.f, 0.f, 0.f, 0.f);
        if (ca < C2) av = *(const float4*)(&fwd[(long)ca * NFFT + k0 + la_k]);
        As[la_k + 0][la_r] = av.x;
        As[la_k + 1][la_r] = av.y;
        As[la_k + 2][la_r] = av.z;
        As[la_k + 3][la_r] = av.w;
        // B tile: frame samples (reflect-padded audio)
        int fb = f0 + la_r;
        float bv[4] = {0.f, 0.f, 0.f, 0.f};
        if (fb < NFR) {
            int pbase = fb * HOP + k0 + la_k - 512;
            #pragma unroll
            for (int q = 0; q < 4; ++q) bv[q] = ab[reflect_idx(pbase + q)];
        }
        Bs[la_k + 0][la_r] = bv[0];
        Bs[la_k + 1][la_r] = bv[1];
        Bs[la_k + 2][la_r] = bv[2];
        Bs[la_k + 3][la_r] = bv[3];
        __syncthreads();
        #pragma unroll
        for (int kk = 0; kk < TKS; ++kk) {
            float4 a  = *(const float4*)(&As[kk][ty << 2]);
            float4 bb = *(const float4*)(&Bs[kk][tx << 2]);
            float ar[4] = {a.x, a.y, a.z, a.w};
            float br[4] = {bb.x, bb.y, bb.z, bb.w};
            #pragma unroll
            for (int i = 0; i < 4; ++i)
                #pragma unroll
                for (int j = 0; j < 4; ++j)
                    acc[i][j] += ar[i] * br[j];
        }
        __syncthreads();
    }
    long base = (long)b * C2 * NFR;
    #pragma unroll
    for (int i = 0; i < 4; ++i) {
        int c = c0 + (ty << 2) + i;
        if (c >= C2) continue;
        #pragma unroll
        for (int j = 0; j < 4; ++j) {
            int f = f0 + (tx << 2) + j;
            if (f < NFR) ft[base + (long)c * NFR + f] = acc[i][j];
        }
    }
}

// in-place spectral scale:  s = max(mag - 0.1*bias, 0) / mag
__global__ void nonlin_k(float* __restrict__ ft, const float* __restrict__ bias) {
    int idx = blockIdx.x * blockDim.x + threadIdx.x;
    const int total = NB * CUT * NFR;
    if (idx >= total) return;
    int f = idx % NFR;
    int t = idx / NFR;
    int k = t % CUT;
    int b = t / CUT;
    long base = (long)b * C2 * NFR + (long)k * NFR + f;
    float re = ft[base];
    float im = ft[base + (long)CUT * NFR];
    float mag = sqrtf(re * re + im * im);
    float md = fmaxf(mag - bias[k] * 0.1f, 0.0f);
    float s = (mag > 0.0f) ? (md / mag) : 0.0f;
    ft[base] = re * s;
    ft[base + (long)CUT * NFR] = im * s;
}

// y[b,f,n] = sum_c invt[n,c] * rec[b,c,f]
__global__ __launch_bounds__(256) void gemm_inv_k(const float* __restrict__ invt,
                                                  const float* __restrict__ rec,
                                                  float* __restrict__ y) {
    __shared__ float As[TKS][TILE + 4];  // [kk][n_local]
    __shared__ float Bs[TKS][TILE + 4];  // [kk][f_local]
    int tid = threadIdx.x;
    int tx = tid & 15, ty = tid >> 4;
    int n0 = blockIdx.y * TILE;
    int f0 = blockIdx.x * TILE;
    int b  = blockIdx.z;
    const float* recb = rec + (long)b * C2 * NFR;
    float acc[4][4] = {};
    int la_r = tid >> 2;
    int la_k = (tid & 3) * 4;

    for (int k0 = 0; k0 < C2; k0 += TKS) {  // 65 iters; tail k0=1024 (2 valid)
        // A tile: invt[n0+la_r][k0+la_k .. +3]  (row stride 1026 -> scalar loads)
        int na = n0 + la_r;
        #pragma unroll
        for (int q = 0; q < 4; ++q) {
            int c = k0 + la_k + q;
            As[la_k + q][la_r] = (c < C2) ? invt[(long)na * C2 + c] : 0.f;
        }
        // B tile: rec[c][f], coalesced along f
        int ff = tid & 63;
        int fg = f0 + ff;
        #pragma unroll
        for (int l = 0; l < 4; ++l) {
            int kk = (tid >> 6) + l * 4;
            int c = k0 + kk;
            float v = 0.f;
            if (c < C2 && fg < NFR) v = recb[(long)c * NFR + fg];
            Bs[kk][ff] = v;
        }
        __syncthreads();
        #pragma unroll
        for (int kk = 0; kk < TKS; ++kk) {
            float4 a  = *(const float4*)(&As[kk][ty << 2]);
            float4 bb = *(const float4*)(&Bs[kk][tx << 2]);
            float ar[4] = {a.x, a.y, a.z, a.w};
            float br[4] = {bb.x, bb.y, bb.z, bb.w};
            #pragma unroll
            for (int i = 0; i < 4; ++i)
                #pragma unroll
                for (int j = 0; j < 4; ++j)
                    acc[i][j] += ar[i] * br[j];
        }
        __syncthreads();
    }
    #pragma unroll
    for (int j = 0; j < 4; ++j) {
        int f = f0 + (tx << 2) + j;
        if (f >= NFR) continue;
        float4 v = make_float4(acc[0][j], acc[1][j], acc[2][j], acc[3][j]);
        *(float4*)(&y[((long)b * NFR + f) * NFFT + n0 + (ty << 2)]) = v;
    }
}

// out[b,i] = OLA(y)[t=i+512] / ws[t] * 4
__global__ void ola_k(const float* __restrict__ y, float* __restrict__ out) {
    int idx = blockIdx.x * blockDim.x + threadIdx.x;
    if (idx >= NB * LAUD) return;
    int i = idx & (LAUD - 1);
    int b = idx >> 20;
    int t = i + 512;
    int ftop = t >> 8;
    int n0 = t & 255;
    const float CST = 6.135923151542565e-3f;
    float acc = 0.f, ws = 0.f;
    #pragma unroll
    for (int d = 0; d < 4; ++d) {
        int f = ftop - d;
        if (f >= 0 && f < NFR) {
            int n = n0 + d * 256;
            acc += y[((long)b * NFR + f) * NFFT + n];
            float w = 0.5f - 0.5f * cosf(CST * (float)n);
            ws += w * w;
        }
    }
    float r = (ws > 1.1754943508e-38f) ? (acc / ws) : acc;
    out[idx] = r * 4.0f;
}

extern "C" void kernel_launch(void* const* d_in, const int* in_sizes, int n_in,
                              void* d_out, int out_size, void* d_ws, size_t ws_size,
                              hipStream_t stream) {
    const float* audio = (const float*)d_in[0];
    const float* bias  = (const float*)d_in[1];
    float* out = (float*)d_out;
    float* wsf = (float*)d_ws;

    float* fwd  = wsf;
    float* invt = wsf + 1050624;
    float* ft   = wsf + 2101248;
    float* y    = wsf + 18915336;

    build_bases_k<<<(C2 * NFFT + 255) / 256, 256, 0, stream>>>(fwd, invt);

    dim3 gf((NFR + TILE - 1) / TILE, (C2 + TILE - 1) / TILE, NB);
    gemm_fwd_k<<<gf, 256, 0, stream>>>(fwd, audio, ft);

    int nl = NB * CUT * NFR;
    nonlin_k<<<(nl + 255) / 256, 256, 0, stream>>>(ft, bias);

    dim3 gi((NFR + TILE - 1) / TILE, NFFT / TILE, NB);
    gemm_inv_k<<<gi, 256, 0, stream>>>(invt, ft, y);

    ola_k<<<(NB * LAUD + 255) / 256, 256, 0, stream>>>(y, out);
}

// Round 2
// 177.750 us; speedup vs baseline: 7.9025x; 7.9025x over previous
//
#include <hip/hip_runtime.h>
#include <math.h>

// Denoiser: STFT -> spectral bias-subtract -> iSTFT, all GEMMs as bf16 MFMA.
// Channel remap drops the two identically-zero im rows: M = K = 1024 exactly.
//   c in [0,513)    -> re_c
//   c in [513,1024) -> im_{c-512}
//
// Workspace (bytes):
//   fwd_bf  @ 0          : 1024*1024*2 = 2 MB      forward basis [c][k] bf16
//   invt_bf @ 2,097,152  : 1024*1024*2 = 2 MB      inverse basis [n][c] bf16
//   aud_bf  @ 4,194,304  : 4*1,082,368*2 = 8.66 MB reflect-padded audio bf16
//   ft      @ 12,853,248 : 4*4224*1024*2 = 34.6 MB spectrum [b][f][c] bf16
//   y       @ 47,456,256 : 4*4224*1024*4 = 69.2 MB frames  [b][f][n] f32
// total 116.7 MB

#define NFFT 1024
#define HOP  256
#define CUT  513
#define NB   4
#define LAUD 1048576
#define NFR  4097
#define NFRP 4224      // 33 tiles of 128
#define ABLEN 1082368  // padded bf16 audio length per batch

typedef __attribute__((ext_vector_type(4))) float f32x4;
typedef __attribute__((ext_vector_type(8))) short bf16x8;

__device__ __forceinline__ unsigned short f2bf(float x) {
    unsigned u = __float_as_uint(x);
    u += 0x7FFF + ((u >> 16) & 1);   // RNE
    return (unsigned short)(u >> 16);
}
__device__ __forceinline__ float bf2f(unsigned short h) {
    return __uint_as_float(((unsigned)h) << 16);
}

__global__ void build_bases_k(ushort* __restrict__ fwd, ushort* __restrict__ invt) {
    int idx = blockIdx.x * blockDim.x + threadIdx.x;
    if (idx >= 1024 * 1024) return;
    int c = idx >> 10, n = idx & 1023;
    const float CST = 6.135923151542565e-3f;  // 2*pi/1024
    float win = 0.5f - 0.5f * cosf(CST * (float)n);
    int k = (c < CUT) ? c : (c - 512);
    int m = (k * n) & 1023;                   // exact periodic reduction
    float si, co;
    sincosf(CST * (float)m, &si, &co);
    float base = (c < CUT) ? co : -si;
    fwd[idx] = f2bf(base * win);
    float d = (c == 0 || c == 512) ? (1.0f / 1024.0f) : (2.0f / 1024.0f);
    invt[(n << 10) + c] = f2bf(0.25f * base * d * win);
}

__global__ void cvt_audio_k(const float* __restrict__ audio, ushort* __restrict__ aud) {
    int idx = blockIdx.x * blockDim.x + threadIdx.x;
    if (idx >= NB * ABLEN) return;
    int t = idx % ABLEN;
    int b = idx / ABLEN;
    float v = 0.f;
    if (t < LAUD + 1024) {
        int j = t - 512;
        if (j < 0) j = -j;
        if (j >= LAUD) j = 2 * LAUD - 2 - j;
        v = audio[(long)b * LAUD + j];
    }
    aud[idx] = f2bf(v);
}

// ---- MFMA GEMM 1: ft[b][f][c] = sum_k fwd[c][k] * frame[b][f][k] ------------
// 128x128 tile, BK=64, 4 waves (2x2), global_load_lds w=16, XOR slot swizzle.
__global__ __launch_bounds__(256) void gemm_fwd_k(
    const ushort* __restrict__ fwd, const ushort* __restrict__ aud,
    ushort* __restrict__ ft) {
    __shared__ char smem[32768];  // A tile 16K | B tile 16K
    const int tid = threadIdx.x;
    const int wid = tid >> 6, lane = tid & 63;
    const int lh = lane & 15, lg = lane >> 4;
    const int wm = wid >> 1, wn = wid & 1;
    const int f0 = blockIdx.x << 7;
    const int c0 = blockIdx.y << 7;
    const int b  = blockIdx.z;
    const ushort* ab = aud + (long)b * ABLEN;
    f32x4 acc[4][4] = {};

    for (int k0 = 0; k0 < 1024; k0 += 64) {
        if (k0) __syncthreads();
        #pragma unroll
        for (int i = 0; i < 4; ++i) {
            int ci = (i << 8) + tid;
            int row = ci >> 3;
            int ks = k0 + (((ci & 7) ^ (row & 7)) << 3);  // pre-swizzled source
            __builtin_amdgcn_global_load_lds(
                (const __attribute__((address_space(1))) unsigned int*)(fwd + ((c0 + row) << 10) + ks),
                (__attribute__((address_space(3))) unsigned int*)(smem + (i << 12) + (wid << 10)),
                16, 0, 0);
            __builtin_amdgcn_global_load_lds(
                (const __attribute__((address_space(1))) unsigned int*)(ab + (f0 + row) * HOP + ks),
                (__attribute__((address_space(3))) unsigned int*)(smem + 16384 + (i << 12) + (wid << 10)),
                16, 0, 0);
        }
        __syncthreads();
        #pragma unroll
        for (int s = 0; s < 2; ++s) {
            bf16x8 av[4], bv[4];
            #pragma unroll
            for (int i = 0; i < 4; ++i) {
                int r = (wm << 6) + (i << 4) + lh;
                av[i] = *(const bf16x8*)(smem + (r << 7) + ((((s << 2) + lg) ^ (r & 7)) << 4));
                int q = (wn << 6) + (i << 4) + lh;
                bv[i] = *(const bf16x8*)(smem + 16384 + (q << 7) + ((((s << 2) + lg) ^ (q & 7)) << 4));
            }
            #pragma unroll
            for (int i = 0; i < 4; ++i)
                #pragma unroll
                for (int j = 0; j < 4; ++j)
                    acc[i][j] = __builtin_amdgcn_mfma_f32_16x16x32_bf16(av[i], bv[j], acc[i][j], 0, 0, 0);
        }
    }
    ushort* ftb = ft + (long)b * NFRP * 1024;
    #pragma unroll
    for (int i = 0; i < 4; ++i) {
        int c = c0 + (wm << 6) + (i << 4) + (lg << 2);
        #pragma unroll
        for (int j = 0; j < 4; ++j) {
            int f = f0 + (wn << 6) + (j << 4) + lh;
            ushort4 o;
            o.x = f2bf(acc[i][j][0]); o.y = f2bf(acc[i][j][1]);
            o.z = f2bf(acc[i][j][2]); o.w = f2bf(acc[i][j][3]);
            *(ushort4*)(ftb + ((long)f << 10) + c) = o;
        }
    }
}

// ---- nonlin: s = max(mag - 0.1*bias, 0)/mag, in-place on ft[b][f][c] --------
__global__ void nonlin_k(ushort* __restrict__ ft, const float* __restrict__ bias) {
    int idx = blockIdx.x * blockDim.x + threadIdx.x;
    if (idx >= NB * NFR * CUT) return;
    int k = idx % CUT;
    int r = idx / CUT;
    int f = r % NFR;
    int b = r / NFR;
    ushort* row = ft + ((long)(b * NFRP + f) << 10);
    float bs = bias[k] * 0.1f;
    if (k == 0 || k == 512) {
        float re = bf2f(row[k]);
        float mag = fabsf(re);
        float s = mag > 0.f ? fmaxf(mag - bs, 0.f) / mag : 0.f;
        row[k] = f2bf(re * s);
    } else {
        float re = bf2f(row[k]), im = bf2f(row[512 + k]);
        float mag = sqrtf(re * re + im * im);
        float s = mag > 0.f ? fmaxf(mag - bs, 0.f) / mag : 0.f;
        row[k] = f2bf(re * s);
        row[512 + k] = f2bf(im * s);
    }
}

// ---- MFMA GEMM 2: y[b][f][n] = sum_c invt[n][c] * ft[b][f][c] ---------------
__global__ __launch_bounds__(256) void gemm_inv_k(
    const ushort* __restrict__ invt, const ushort* __restrict__ ft,
    float* __restrict__ y) {
    __shared__ char smem[32768];
    const int tid = threadIdx.x;
    const int wid = tid >> 6, lane = tid & 63;
    const int lh = lane & 15, lg = lane >> 4;
    const int wm = wid >> 1, wn = wid & 1;
    const int f0 = blockIdx.x << 7;
    const int n0 = blockIdx.y << 7;
    const int b  = blockIdx.z;
    const ushort* rb = ft + (long)b * NFRP * 1024;
    f32x4 acc[4][4] = {};

    for (int k0 = 0; k0 < 1024; k0 += 64) {
        if (k0) __syncthreads();
        #pragma unroll
        for (int i = 0; i < 4; ++i) {
            int ci = (i << 8) + tid;
            int row = ci >> 3;
            int ks = k0 + (((ci & 7) ^ (row & 7)) << 3);
            __builtin_amdgcn_global_load_lds(
                (const __attribute__((address_space(1))) unsigned int*)(invt + ((n0 + row) << 10) + ks),
                (__attribute__((address_space(3))) unsigned int*)(smem + (i << 12) + (wid << 10)),
                16, 0, 0);
            __builtin_amdgcn_global_load_lds(
                (const __attribute__((address_space(1))) unsigned int*)(rb + ((long)(f0 + row) << 10) + ks),
                (__attribute__((address_space(3))) unsigned int*)(smem + 16384 + (i << 12) + (wid << 10)),
                16, 0, 0);
        }
        __syncthreads();
        #pragma unroll
        for (int s = 0; s < 2; ++s) {
            bf16x8 av[4], bv[4];
            #pragma unroll
            for (int i = 0; i < 4; ++i) {
                int r = (wm << 6) + (i << 4) + lh;
                av[i] = *(const bf16x8*)(smem + (r << 7) + ((((s << 2) + lg) ^ (r & 7)) << 4));
                int q = (wn << 6) + (i << 4) + lh;
                bv[i] = *(const bf16x8*)(smem + 16384 + (q << 7) + ((((s << 2) + lg) ^ (q & 7)) << 4));
            }
            #pragma unroll
            for (int i = 0; i < 4; ++i)
                #pragma unroll
                for (int j = 0; j < 4; ++j)
                    acc[i][j] = __builtin_amdgcn_mfma_f32_16x16x32_bf16(av[i], bv[j], acc[i][j], 0, 0, 0);
        }
    }
    float* yb = y + (long)b * NFRP * 1024;
    #pragma unroll
    for (int i = 0; i < 4; ++i) {
        int n = n0 + (wm << 6) + (i << 4) + (lg << 2);
        #pragma unroll
        for (int j = 0; j < 4; ++j) {
            int f = f0 + (wn << 6) + (j << 4) + lh;
            *(f32x4*)(yb + ((long)f << 10) + n) = acc[i][j];
        }
    }
}

// ---- overlap-add with analytic window-sum normalization ---------------------
__global__ void ola_k(const float* __restrict__ y, float* __restrict__ out) {
    int idx = blockIdx.x * blockDim.x + threadIdx.x;
    if (idx >= NB * LAUD) return;
    int i = idx & (LAUD - 1);
    int b = idx >> 20;
    int t = i + 512;
    int ftop = t >> 8, nn0 = t & 255;
    const float CST = 6.135923151542565e-3f;
    const float* yb = y + (long)b * NFRP * 1024;
    float acc = 0.f, wsum = 0.f;
    #pragma unroll
    for (int d = 0; d < 4; ++d) {
        int f = ftop - d;
        if (f >= 0 && f < NFR) {
            int n = nn0 + (d << 8);
            acc += yb[((long)f << 10) + n];
            float w = 0.5f - 0.5f * cosf(CST * (float)n);
            wsum += w * w;
        }
    }
    out[idx] = ((wsum > 1.1754943508e-38f) ? (acc / wsum) : acc) * 4.0f;
}

extern "C" void kernel_launch(void* const* d_in, const int* in_sizes, int n_in,
                              void* d_out, int out_size, void* d_ws, size_t ws_size,
                              hipStream_t stream) {
    const float* audio = (const float*)d_in[0];
    const float* bias  = (const float*)d_in[1];
    float* out = (float*)d_out;
    char* wsb = (char*)d_ws;

    ushort* fwd  = (ushort*)(wsb);
    ushort* invt = (ushort*)(wsb + 2097152);
    ushort* aud  = (ushort*)(wsb + 4194304);
    ushort* ft   = (ushort*)(wsb + 12853248);
    float*  y    = (float*)(wsb + 47456256);

    build_bases_k<<<4096, 256, 0, stream>>>(fwd, invt);
    cvt_audio_k<<<(NB * ABLEN + 255) / 256, 256, 0, stream>>>(audio, aud);

    dim3 g(NFRP / 128, 1024 / 128, NB);
    gemm_fwd_k<<<g, 256, 0, stream>>>(fwd, aud, ft);

    nonlin_k<<<(NB * NFR * CUT + 255) / 256, 256, 0, stream>>>(ft, bias);

    gemm_inv_k<<<g, 256, 0, stream>>>(invt, ft, y);

    ola_k<<<(NB * LAUD + 255) / 256, 256, 0, stream>>>(y, out);
}

// Round 4
// 135.999 us; speedup vs baseline: 10.3286x; 1.3070x over previous
//
#include <hip/hip_runtime.h>
#include <math.h>

// Denoiser, fully fused:
//   K1: build bases (fwd DFT basis, OLA-folded inverse basis W)
//   K2: reflect-pad + bf16-cast audio
//   K3: zero ft row 0 (virtual frame -1)
//   K4: GEMM1 (STFT) + fused spectral nonlin epilogue -> ft bf16
//       (frames >= NFR store ZERO: GEMM2 edge normalization requires it)
//   K5: GEMM2 (iSTFT folded with OLA: W is 256x4096) -> final output f32
//
// Channel map (M=K=1024, no zero rows): c in [0,513) = re_c ; 512+k = im_k (k>=1).
// GEMM2: out[fo*256+h-512] = sum_{d,c} W[h][d*1024+c] * ft[fo-d+1][c],
//        fo in [2,4097]; ft row f' = frame f+1, rows 0 and >=4098 are zero.
//
// Workspace:
//   fwd  @ 0          : 1024*1024*2 = 2 MB
//   invW @ 2,097,152  : 256*4096*2  = 2 MB
//   aud  @ 4,194,304  : 4*1,082,368*2 = 8.66 MB
//   ft   @ 12,853,248 : 4*4232*1024*2 = 34.67 MB   (ends 47.5 MB)

#define NFFT 1024
#define HOP  256
#define CUT  513
#define NB   4
#define LAUD 1048576
#define NFR  4097
#define NFRP 4224      // 33 tiles of 128 (frames >= 4097 are stored as zero)
#define FTROWS 4232    // per-batch ft rows (row 0 = zero frame -1)
#define ABLEN 1082368

typedef __attribute__((ext_vector_type(4))) float f32x4;
typedef __attribute__((ext_vector_type(8))) short bf16x8;

__device__ __forceinline__ unsigned short f2bf(float x) {
    unsigned u = __float_as_uint(x);
    u += 0x7FFF + ((u >> 16) & 1);   // RNE
    return (unsigned short)(u >> 16);
}

__global__ void build_bases_k(ushort* __restrict__ fwd, ushort* __restrict__ invW) {
    int idx = blockIdx.x * blockDim.x + threadIdx.x;
    if (idx >= 1024 * 1024) return;
    int c = idx >> 10, n = idx & 1023;
    const float CST = 6.135923151542565e-3f;  // 2*pi/1024
    float win = 0.5f - 0.5f * cosf(CST * (float)n);
    int k = (c < CUT) ? c : (c - 512);
    int m = (k * n) & 1023;                   // exact periodic reduction
    float si, co;
    sincosf(CST * (float)m, &si, &co);
    float base = (c < CUT) ? co : -si;
    fwd[idx] = f2bf(base * win);
    float d = (c == 0 || c == 512) ? (1.0f / 1024.0f) : (2.0f / 1024.0f);
    // W[h][dd*1024 + c] = invt[n = h+256*dd][c]
    invW[((n & 255) << 12) + ((n >> 8) << 10) + c] = f2bf(0.25f * base * d * win);
}

__global__ void cvt_audio_k(const float* __restrict__ audio, ushort* __restrict__ aud) {
    int idx = blockIdx.x * blockDim.x + threadIdx.x;
    if (idx >= NB * ABLEN) return;
    int t = idx % ABLEN;
    int b = idx / ABLEN;
    float v = 0.f;
    if (t < LAUD + 1024) {
        int j = t - 512;
        if (j < 0) j = -j;
        if (j >= LAUD) j = 2 * LAUD - 2 - j;
        v = audio[(long)b * LAUD + j];
    }
    aud[idx] = f2bf(v);
}

__global__ void zero_row_k(ushort* __restrict__ ft) {
    int idx = blockIdx.x * blockDim.x + threadIdx.x;
    if (idx >= NB * 1024) return;
    int b = idx >> 10, c = idx & 1023;
    ft[(long)b * FTROWS * 1024 + c] = 0;
}

// ---- GEMM1: STFT + fused nonlin --------------------------------------------
// A-tile rows interleaved: local row r -> group g=r>>4 (even: re, odd: im).
// global channel = (g&1)*512 + c0 + (g>>1)*16 + (r&15),  c0 = blockIdx.y*64.
__global__ __launch_bounds__(256) void gemm_fwd_k(
    const ushort* __restrict__ fwd, const ushort* __restrict__ aud,
    const float* __restrict__ bias, ushort* __restrict__ ft) {
    __shared__ char smem[32768];  // A 16K | B 16K
    const int tid = threadIdx.x;
    const int wid = tid >> 6, lane = tid & 63;
    const int lh = lane & 15, lg = lane >> 4;
    const int wm = wid >> 1, wn = wid & 1;
    const int f0 = blockIdx.x << 7;
    const int c0 = blockIdx.y << 6;
    const int b  = blockIdx.z;
    const ushort* ab = aud + (long)b * ABLEN;
    f32x4 acc[4][4] = {};

    for (int k0 = 0; k0 < 1024; k0 += 64) {
        if (k0) __syncthreads();
        #pragma unroll
        for (int i = 0; i < 4; ++i) {
            int ci = (i << 8) + tid;
            int row = ci >> 3;
            int ks = k0 + (((ci & 7) ^ (row & 7)) << 3);  // pre-swizzled source
            int grow = ((row >> 4) & 1) * 512 + c0 + ((row >> 5) << 4) + (row & 15);
            __builtin_amdgcn_global_load_lds(
                (const __attribute__((address_space(1))) unsigned int*)(fwd + (grow << 10) + ks),
                (__attribute__((address_space(3))) unsigned int*)(smem + (i << 12) + (wid << 10)),
                16, 0, 0);
            __builtin_amdgcn_global_load_lds(
                (const __attribute__((address_space(1))) unsigned int*)(ab + (f0 + row) * HOP + ks),
                (__attribute__((address_space(3))) unsigned int*)(smem + 16384 + (i << 12) + (wid << 10)),
                16, 0, 0);
        }
        __syncthreads();
        #pragma unroll
        for (int s = 0; s < 2; ++s) {
            bf16x8 av[4], bv[4];
            #pragma unroll
            for (int i = 0; i < 4; ++i) {
                int r = (wm << 6) + (i << 4) + lh;
                av[i] = *(const bf16x8*)(smem + (r << 7) + ((((s << 2) + lg) ^ (r & 7)) << 4));
                int q = (wn << 6) + (i << 4) + lh;
                bv[i] = *(const bf16x8*)(smem + 16384 + (q << 7) + ((((s << 2) + lg) ^ (q & 7)) << 4));
            }
            #pragma unroll
            for (int i = 0; i < 4; ++i)
                #pragma unroll
                for (int j = 0; j < 4; ++j)
                    acc[i][j] = __builtin_amdgcn_mfma_f32_16x16x32_bf16(av[i], bv[j], acc[i][j], 0, 0, 0);
        }
    }
    // fused nonlin epilogue: pairs (acc[2p], acc[2p+1]) = (re, im) rows.
    ushort* ftb = ft + (long)b * FTROWS * 1024 + 1024;  // f' = f+1
    float b512 = bias[512] * 0.1f;
    #pragma unroll
    for (int p = 0; p < 2; ++p) {
        int kbase = c0 + ((wm * 2 + p) << 4) + (lg << 2);
        float bs[4];
        #pragma unroll
        for (int q = 0; q < 4; ++q) bs[q] = bias[kbase + q] * 0.1f;
        #pragma unroll
        for (int j = 0; j < 4; ++j) {
            int f = f0 + (wn << 6) + (j << 4) + lh;
            bool valid = (f < NFR);   // frames >= NFR must be stored as ZERO
            ushort4 ore, oim;
            #pragma unroll
            for (int q = 0; q < 4; ++q) {
                float re = acc[2 * p][j][q], im = acc[2 * p + 1][j][q];
                float sre, sim;
                if (kbase + q == 0) {  // re_0 and re_512: independent lone channels
                    float mre = fabsf(re), mim = fabsf(im);
                    sre = mre > 0.f ? fmaxf(mre - bs[0], 0.f) / mre : 0.f;
                    sim = mim > 0.f ? fmaxf(mim - b512, 0.f) / mim : 0.f;
                } else {
                    float mag = sqrtf(re * re + im * im);
                    float s = mag > 0.f ? fmaxf(mag - bs[q], 0.f) / mag : 0.f;
                    sre = s; sim = s;
                }
                float vre = valid ? re * sre : 0.f;
                float vim = valid ? im * sim : 0.f;
                ((unsigned short*)&ore)[q] = f2bf(vre);
                ((unsigned short*)&oim)[q] = f2bf(vim);
            }
            *(ushort4*)(ftb + ((long)f << 10) + kbase) = ore;
            *(ushort4*)(ftb + ((long)f << 10) + 512 + kbase) = oim;
        }
    }
}

// ---- GEMM2: iSTFT + OLA folded (M=256 h, K=4096 dc, N=fo) -------------------
__global__ __launch_bounds__(256) void gemm_ola_k(
    const ushort* __restrict__ invW, const ushort* __restrict__ ft,
    float* __restrict__ out) {
    __shared__ char smem[24576];  // A 16K (128x64) | B 8K (64x64)
    const int tid = threadIdx.x;
    const int wid = tid >> 6, lane = tid & 63;
    const int lh = lane & 15, lg = lane >> 4;
    const int wm = wid >> 1, wn = wid & 1;
    const int fo0 = 2 + (blockIdx.x << 6);
    const int h0  = blockIdx.y << 7;
    const int b   = blockIdx.z;
    const ushort* ftb = ft + (long)b * FTROWS * 1024;
    f32x4 acc[4][2] = {};

    for (int k0 = 0; k0 < 4096; k0 += 64) {
        if (k0) __syncthreads();
        int d  = k0 >> 10;
        int cb = k0 & 1023;
        #pragma unroll
        for (int i = 0; i < 4; ++i) {  // A: W rows h0..h0+127
            int ci = (i << 8) + tid;
            int row = ci >> 3;
            int swz = (((ci & 7) ^ (row & 7)) << 3);
            __builtin_amdgcn_global_load_lds(
                (const __attribute__((address_space(1))) unsigned int*)(invW + ((h0 + row) << 12) + k0 + swz),
                (__attribute__((address_space(3))) unsigned int*)(smem + (i << 12) + (wid << 10)),
                16, 0, 0);
        }
        #pragma unroll
        for (int i = 0; i < 2; ++i) {  // B: rec rows fo0-d+1 .. +63
            int ci = (i << 8) + tid;
            int row = ci >> 3;
            int swz = (((ci & 7) ^ (row & 7)) << 3);
            int frow = fo0 + row - d + 1;
            __builtin_amdgcn_global_load_lds(
                (const __attribute__((address_space(1))) unsigned int*)(ftb + ((long)frow << 10) + cb + swz),
                (__attribute__((address_space(3))) unsigned int*)(smem + 16384 + (i << 12) + (wid << 10)),
                16, 0, 0);
        }
        __syncthreads();
        #pragma unroll
        for (int s = 0; s < 2; ++s) {
            bf16x8 av[4], bv[2];
            #pragma unroll
            for (int i = 0; i < 4; ++i) {
                int r = (wm << 6) + (i << 4) + lh;
                av[i] = *(const bf16x8*)(smem + (r << 7) + ((((s << 2) + lg) ^ (r & 7)) << 4));
            }
            #pragma unroll
            for (int j = 0; j < 2; ++j) {
                int rq = (wn << 5) + (j << 4) + lh;
                bv[j] = *(const bf16x8*)(smem + 16384 + (rq << 7) + ((((s << 2) + lg) ^ (rq & 7)) << 4));
            }
            #pragma unroll
            for (int i = 0; i < 4; ++i)
                #pragma unroll
                for (int j = 0; j < 2; ++j)
                    acc[i][j] = __builtin_amdgcn_mfma_f32_16x16x32_bf16(av[i], bv[j], acc[i][j], 0, 0, 0);
        }
    }
    float* ob = out + (long)b * LAUD;
    const float CST = 6.135923151542565e-3f;
    #pragma unroll
    for (int i = 0; i < 4; ++i) {
        int hbase = h0 + (wm << 6) + (i << 4) + (lg << 2);
        #pragma unroll
        for (int j = 0; j < 2; ++j) {
            int fo = fo0 + (wn << 5) + (j << 4) + lh;
            f32x4 v = acc[i][j];
            if (fo == 2 || fo == 4097) {       // partial window-sum at the edges
                #pragma unroll
                for (int q = 0; q < 4; ++q) {
                    int n = (fo == 2) ? (hbase + q + 768) : (hbase + q);
                    float w = 0.5f - 0.5f * cosf(CST * (float)n);
                    v[q] = v[q] * (4.0f / (1.5f - w * w));
                }
            } else {
                v *= (8.0f / 3.0f);            // interior: ws == 1.5 exactly
            }
            *(f32x4*)(ob + (((long)(fo - 2)) << 8) + hbase) = v;
        }
    }
}

extern "C" void kernel_launch(void* const* d_in, const int* in_sizes, int n_in,
                              void* d_out, int out_size, void* d_ws, size_t ws_size,
                              hipStream_t stream) {
    const float* audio = (const float*)d_in[0];
    const float* bias  = (const float*)d_in[1];
    float* out = (float*)d_out;
    char* wsb = (char*)d_ws;

    ushort* fwd  = (ushort*)(wsb);
    ushort* invW = (ushort*)(wsb + 2097152);
    ushort* aud  = (ushort*)(wsb + 4194304);
    ushort* ft   = (ushort*)(wsb + 12853248);

    build_bases_k<<<4096, 256, 0, stream>>>(fwd, invW);
    cvt_audio_k<<<(NB * ABLEN + 255) / 256, 256, 0, stream>>>(audio, aud);
    zero_row_k<<<(NB * 1024 + 255) / 256, 256, 0, stream>>>(ft);

    dim3 g1(NFRP / 128, 8, NB);   // f-tiles x c-pair-tiles x b
    gemm_fwd_k<<<g1, 256, 0, stream>>>(fwd, aud, bias, ft);

    dim3 g2(64, 2, NB);           // fo-tiles x h-tiles x b
    gemm_ola_k<<<g2, 256, 0, stream>>>(invW, ft, out);
}

// Round 5
// 124.194 us; speedup vs baseline: 11.3103x; 1.0950x over previous
//
#include <hip/hip_runtime.h>
#include <math.h>

// Denoiser, fully fused:
//   K1: build bases (fwd DFT basis, OLA-folded inverse basis W)
//   K2: reflect-pad + bf16-cast audio
//   K3: zero ft row 0 (virtual frame -1)
//   K4: GEMM1 (STFT) + fused spectral nonlin epilogue -> ft bf16
//       (frames >= NFR store ZERO: GEMM2 edge normalization requires it)
//   K5: GEMM2 (iSTFT folded with OLA: W is 256x4096) -> final output f32.
//       8 waves: K split across two 4-wave groups (d{0,1} | d{2,3}),
//       combined through LDS at the end. 2x occupancy vs 4-wave version.
//
// Channel map (M=K=1024, no zero rows): c in [0,513) = re_c ; 512+k = im_k (k>=1).
// GEMM2: out[fo*256+h-512] = sum_{d,c} W[h][d*1024+c] * ft[fo-d+1][c],
//        fo in [2,4097]; ft row f' = frame f+1, rows 0 and >=4098 are zero.
//
// Workspace:
//   fwd  @ 0          : 1024*1024*2 = 2 MB
//   invW @ 2,097,152  : 256*4096*2  = 2 MB
//   aud  @ 4,194,304  : 4*1,082,368*2 = 8.66 MB
//   ft   @ 12,853,248 : 4*4232*1024*2 = 34.67 MB   (ends 47.5 MB)

#define NFFT 1024
#define HOP  256
#define CUT  513
#define NB   4
#define LAUD 1048576
#define NFR  4097
#define NFRP 4224      // 33 tiles of 128 (frames >= 4097 are stored as zero)
#define FTROWS 4232    // per-batch ft rows (row 0 = zero frame -1)
#define ABLEN 1082368

typedef __attribute__((ext_vector_type(4))) float f32x4;
typedef __attribute__((ext_vector_type(8))) short bf16x8;

__device__ __forceinline__ unsigned short f2bf(float x) {
    unsigned u = __float_as_uint(x);
    u += 0x7FFF + ((u >> 16) & 1);   // RNE
    return (unsigned short)(u >> 16);
}

__global__ void build_bases_k(ushort* __restrict__ fwd, ushort* __restrict__ invW) {
    int idx = blockIdx.x * blockDim.x + threadIdx.x;
    if (idx >= 1024 * 1024) return;
    int c = idx >> 10, n = idx & 1023;
    const float CST = 6.135923151542565e-3f;  // 2*pi/1024
    float win = 0.5f - 0.5f * cosf(CST * (float)n);
    int k = (c < CUT) ? c : (c - 512);
    int m = (k * n) & 1023;                   // exact periodic reduction
    float si, co;
    sincosf(CST * (float)m, &si, &co);
    float base = (c < CUT) ? co : -si;
    fwd[idx] = f2bf(base * win);
    float d = (c == 0 || c == 512) ? (1.0f / 1024.0f) : (2.0f / 1024.0f);
    // W[h][dd*1024 + c] = invt[n = h+256*dd][c]
    invW[((n & 255) << 12) + ((n >> 8) << 10) + c] = f2bf(0.25f * base * d * win);
}

__global__ void cvt_audio_k(const float* __restrict__ audio, ushort* __restrict__ aud) {
    int idx = blockIdx.x * blockDim.x + threadIdx.x;
    if (idx >= NB * ABLEN) return;
    int t = idx % ABLEN;
    int b = idx / ABLEN;
    float v = 0.f;
    if (t < LAUD + 1024) {
        int j = t - 512;
        if (j < 0) j = -j;
        if (j >= LAUD) j = 2 * LAUD - 2 - j;
        v = audio[(long)b * LAUD + j];
    }
    aud[idx] = f2bf(v);
}

__global__ void zero_row_k(ushort* __restrict__ ft) {
    int idx = blockIdx.x * blockDim.x + threadIdx.x;
    if (idx >= NB * 1024) return;
    int b = idx >> 10, c = idx & 1023;
    ft[(long)b * FTROWS * 1024 + c] = 0;
}

// ---- GEMM1: STFT + fused nonlin --------------------------------------------
// A-tile rows interleaved: local row r -> group g=r>>4 (even: re, odd: im).
// global channel = (g&1)*512 + c0 + (g>>1)*16 + (r&15),  c0 = blockIdx.y*64.
__global__ __launch_bounds__(256) void gemm_fwd_k(
    const ushort* __restrict__ fwd, const ushort* __restrict__ aud,
    const float* __restrict__ bias, ushort* __restrict__ ft) {
    __shared__ char smem[32768];  // A 16K | B 16K
    const int tid = threadIdx.x;
    const int wid = tid >> 6, lane = tid & 63;
    const int lh = lane & 15, lg = lane >> 4;
    const int wm = wid >> 1, wn = wid & 1;
    const int f0 = blockIdx.x << 7;
    const int c0 = blockIdx.y << 6;
    const int b  = blockIdx.z;
    const ushort* ab = aud + (long)b * ABLEN;
    f32x4 acc[4][4] = {};

    for (int k0 = 0; k0 < 1024; k0 += 64) {
        if (k0) __syncthreads();
        #pragma unroll
        for (int i = 0; i < 4; ++i) {
            int ci = (i << 8) + tid;
            int row = ci >> 3;
            int ks = k0 + (((ci & 7) ^ (row & 7)) << 3);  // pre-swizzled source
            int grow = ((row >> 4) & 1) * 512 + c0 + ((row >> 5) << 4) + (row & 15);
            __builtin_amdgcn_global_load_lds(
                (const __attribute__((address_space(1))) unsigned int*)(fwd + (grow << 10) + ks),
                (__attribute__((address_space(3))) unsigned int*)(smem + (i << 12) + (wid << 10)),
                16, 0, 0);
            __builtin_amdgcn_global_load_lds(
                (const __attribute__((address_space(1))) unsigned int*)(ab + (f0 + row) * HOP + ks),
                (__attribute__((address_space(3))) unsigned int*)(smem + 16384 + (i << 12) + (wid << 10)),
                16, 0, 0);
        }
        __syncthreads();
        #pragma unroll
        for (int s = 0; s < 2; ++s) {
            bf16x8 av[4], bv[4];
            #pragma unroll
            for (int i = 0; i < 4; ++i) {
                int r = (wm << 6) + (i << 4) + lh;
                av[i] = *(const bf16x8*)(smem + (r << 7) + ((((s << 2) + lg) ^ (r & 7)) << 4));
                int q = (wn << 6) + (i << 4) + lh;
                bv[i] = *(const bf16x8*)(smem + 16384 + (q << 7) + ((((s << 2) + lg) ^ (q & 7)) << 4));
            }
            #pragma unroll
            for (int i = 0; i < 4; ++i)
                #pragma unroll
                for (int j = 0; j < 4; ++j)
                    acc[i][j] = __builtin_amdgcn_mfma_f32_16x16x32_bf16(av[i], bv[j], acc[i][j], 0, 0, 0);
        }
    }
    // fused nonlin epilogue: pairs (acc[2p], acc[2p+1]) = (re, im) rows.
    ushort* ftb = ft + (long)b * FTROWS * 1024 + 1024;  // f' = f+1
    float b512 = bias[512] * 0.1f;
    #pragma unroll
    for (int p = 0; p < 2; ++p) {
        int kbase = c0 + ((wm * 2 + p) << 4) + (lg << 2);
        float bs[4];
        #pragma unroll
        for (int q = 0; q < 4; ++q) bs[q] = bias[kbase + q] * 0.1f;
        #pragma unroll
        for (int j = 0; j < 4; ++j) {
            int f = f0 + (wn << 6) + (j << 4) + lh;
            bool valid = (f < NFR);   // frames >= NFR must be stored as ZERO
            ushort4 ore, oim;
            #pragma unroll
            for (int q = 0; q < 4; ++q) {
                float re = acc[2 * p][j][q], im = acc[2 * p + 1][j][q];
                float sre, sim;
                if (kbase + q == 0) {  // re_0 and re_512: independent lone channels
                    float mre = fabsf(re), mim = fabsf(im);
                    sre = mre > 0.f ? fmaxf(mre - bs[0], 0.f) / mre : 0.f;
                    sim = mim > 0.f ? fmaxf(mim - b512, 0.f) / mim : 0.f;
                } else {
                    float mag = sqrtf(re * re + im * im);
                    float s = mag > 0.f ? fmaxf(mag - bs[q], 0.f) / mag : 0.f;
                    sre = s; sim = s;
                }
                float vre = valid ? re * sre : 0.f;
                float vim = valid ? im * sim : 0.f;
                ((unsigned short*)&ore)[q] = f2bf(vre);
                ((unsigned short*)&oim)[q] = f2bf(vim);
            }
            *(ushort4*)(ftb + ((long)f << 10) + kbase) = ore;
            *(ushort4*)(ftb + ((long)f << 10) + 512 + kbase) = oim;
        }
    }
}

// ---- GEMM2: iSTFT + OLA folded (M=256 h, K=4096 dc, N=fo) -------------------
// 512 threads, 8 waves = 2 K-groups of 4 waves. Group g does K in
// [g*2048, g*2048+2048). Each group has a private 24KB staging region;
// group 1's accumulators are combined through LDS at the end.
__global__ __launch_bounds__(512) void gemm_ola_k(
    const ushort* __restrict__ invW, const ushort* __restrict__ ft,
    float* __restrict__ out) {
    __shared__ char smem[49152];  // group0: A 16K | B 8K ; group1 at +24576
    const int tid = threadIdx.x;
    const int wid = tid >> 6, lane = tid & 63;
    const int lh = lane & 15, lg = lane >> 4;
    const int g = wid >> 2;           // K-group
    const int wid2 = wid & 3;
    const int wm = wid2 >> 1, wn = wid2 & 1;
    const int tg = tid & 255;         // tid within group
    const int fo0 = 2 + (blockIdx.x << 6);
    const int h0  = blockIdx.y << 7;
    const int b   = blockIdx.z;
    const ushort* ftb = ft + (long)b * FTROWS * 1024;
    char* sm = smem + g * 24576;
    f32x4 acc[4][2] = {};

    for (int k0 = 0; k0 < 2048; k0 += 64) {
        if (k0) __syncthreads();
        int kk = (g << 11) + k0;
        int d  = kk >> 10;
        int cb = kk & 1023;
        #pragma unroll
        for (int i = 0; i < 4; ++i) {  // A: W rows h0..h0+127
            int ci = (i << 8) + tg;
            int row = ci >> 3;
            int swz = (((ci & 7) ^ (row & 7)) << 3);
            __builtin_amdgcn_global_load_lds(
                (const __attribute__((address_space(1))) unsigned int*)(invW + ((h0 + row) << 12) + kk + swz),
                (__attribute__((address_space(3))) unsigned int*)(sm + (i << 12) + (wid2 << 10)),
                16, 0, 0);
        }
        #pragma unroll
        for (int i = 0; i < 2; ++i) {  // B: rec rows fo0-d+1 .. +63
            int ci = (i << 8) + tg;
            int row = ci >> 3;
            int swz = (((ci & 7) ^ (row & 7)) << 3);
            int frow = fo0 + row - d + 1;
            __builtin_amdgcn_global_load_lds(
                (const __attribute__((address_space(1))) unsigned int*)(ftb + ((long)frow << 10) + cb + swz),
                (__attribute__((address_space(3))) unsigned int*)(sm + 16384 + (i << 12) + (wid2 << 10)),
                16, 0, 0);
        }
        __syncthreads();
        #pragma unroll
        for (int s = 0; s < 2; ++s) {
            bf16x8 av[4], bv[2];
            #pragma unroll
            for (int i = 0; i < 4; ++i) {
                int r = (wm << 6) + (i << 4) + lh;
                av[i] = *(const bf16x8*)(sm + (r << 7) + ((((s << 2) + lg) ^ (r & 7)) << 4));
            }
            #pragma unroll
            for (int j = 0; j < 2; ++j) {
                int rq = (wn << 5) + (j << 4) + lh;
                bv[j] = *(const bf16x8*)(sm + 16384 + (rq << 7) + ((((s << 2) + lg) ^ (rq & 7)) << 4));
            }
            #pragma unroll
            for (int i = 0; i < 4; ++i)
                #pragma unroll
                for (int j = 0; j < 2; ++j)
                    acc[i][j] = __builtin_amdgcn_mfma_f32_16x16x32_bf16(av[i], bv[j], acc[i][j], 0, 0, 0);
        }
    }
    // ---- combine group 1 into group 0 through LDS (32KB f32, [h][fo]) ------
    __syncthreads();
    float* red = (float*)smem;
    if (g == 1) {
        #pragma unroll
        for (int i = 0; i < 4; ++i)
            #pragma unroll
            for (int j = 0; j < 2; ++j) {
                int hl = (wm << 6) + (i << 4) + (lg << 2);
                int fl = (wn << 5) + (j << 4) + lh;
                #pragma unroll
                for (int q = 0; q < 4; ++q)
                    red[(hl + q) * 64 + fl] = acc[i][j][q];
            }
    }
    __syncthreads();
    if (g == 1) return;
    float* ob = out + (long)b * LAUD;
    const float CST = 6.135923151542565e-3f;
    #pragma unroll
    for (int i = 0; i < 4; ++i) {
        int hbase = h0 + (wm << 6) + (i << 4) + (lg << 2);
        int hl = (wm << 6) + (i << 4) + (lg << 2);
        #pragma unroll
        for (int j = 0; j < 2; ++j) {
            int fo = fo0 + (wn << 5) + (j << 4) + lh;
            int fl = (wn << 5) + (j << 4) + lh;
            f32x4 v = acc[i][j];
            #pragma unroll
            for (int q = 0; q < 4; ++q) v[q] += red[(hl + q) * 64 + fl];
            if (fo == 2 || fo == 4097) {       // partial window-sum at the edges
                #pragma unroll
                for (int q = 0; q < 4; ++q) {
                    int n = (fo == 2) ? (hbase + q + 768) : (hbase + q);
                    float w = 0.5f - 0.5f * cosf(CST * (float)n);
                    v[q] = v[q] * (4.0f / (1.5f - w * w));
                }
            } else {
                v *= (8.0f / 3.0f);            // interior: ws == 1.5 exactly
            }
            *(f32x4*)(ob + (((long)(fo - 2)) << 8) + hbase) = v;
        }
    }
}

extern "C" void kernel_launch(void* const* d_in, const int* in_sizes, int n_in,
                              void* d_out, int out_size, void* d_ws, size_t ws_size,
                              hipStream_t stream) {
    const float* audio = (const float*)d_in[0];
    const float* bias  = (const float*)d_in[1];
    float* out = (float*)d_out;
    char* wsb = (char*)d_ws;

    ushort* fwd  = (ushort*)(wsb);
    ushort* invW = (ushort*)(wsb + 2097152);
    ushort* aud  = (ushort*)(wsb + 4194304);
    ushort* ft   = (ushort*)(wsb + 12853248);

    build_bases_k<<<4096, 256, 0, stream>>>(fwd, invW);
    cvt_audio_k<<<(NB * ABLEN + 255) / 256, 256, 0, stream>>>(audio, aud);
    zero_row_k<<<(NB * 1024 + 255) / 256, 256, 0, stream>>>(ft);

    dim3 g1(NFRP / 128, 8, NB);   // f-tiles x c-pair-tiles x b
    gemm_fwd_k<<<g1, 256, 0, stream>>>(fwd, aud, bias, ft);

    dim3 g2(64, 2, NB);           // fo-tiles x h-tiles x b
    gemm_ola_k<<<g2, 512, 0, stream>>>(invW, ft, out);
}

// Round 6
// 115.684 us; speedup vs baseline: 12.1423x; 1.0736x over previous
//
#include <hip/hip_runtime.h>
#include <math.h>

// Denoiser, fully fused:
//   K1: build bases (fwd DFT basis, OLA-folded inverse basis W)
//   K2: reflect-pad + bf16-cast audio
//   K3: zero ft row 0 (virtual frame -1)
//   K4: GEMM1 (STFT) + fused spectral nonlin epilogue -> ft bf16  [XCD-swizzled]
//   K5: GEMM2 (iSTFT folded with OLA, 2-group split-K) -> output  [XCD-swizzled]
//
// Channel map (M=K=1024, no zero rows): c in [0,513) = re_c ; 512+k = im_k (k>=1).
// GEMM2: out[fo*256+h-512] = sum_{d,c} W[h][d*1024+c] * ft[fo-d+1][c],
//        fo in [2,4097]; ft row f' = frame f+1, rows 0 and >=4098 are zero.
//
// Workspace:
//   fwd  @ 0          : 1024*1024*2 = 2 MB
//   invW @ 2,097,152  : 256*4096*2  = 2 MB
//   aud  @ 4,194,304  : 4*1,082,368*2 = 8.66 MB
//   ft   @ 12,853,248 : 4*4232*1024*2 = 34.67 MB   (ends 47.5 MB)

#define NFFT 1024
#define HOP  256
#define CUT  513
#define NB   4
#define LAUD 1048576
#define NFR  4097
#define NFRP 4224      // 33 tiles of 128 (frames >= 4097 are stored as zero)
#define FTROWS 4232    // per-batch ft rows (row 0 = zero frame -1)
#define ABLEN 1082368

typedef __attribute__((ext_vector_type(4))) float f32x4;
typedef __attribute__((ext_vector_type(8))) short bf16x8;

__device__ __forceinline__ unsigned short f2bf(float x) {
    unsigned u = __float_as_uint(x);
    u += 0x7FFF + ((u >> 16) & 1);   // RNE
    return (unsigned short)(u >> 16);
}

__global__ void build_bases_k(ushort* __restrict__ fwd, ushort* __restrict__ invW) {
    int idx = blockIdx.x * blockDim.x + threadIdx.x;
    if (idx >= 1024 * 1024) return;
    int c = idx >> 10, n = idx & 1023;
    const float CST = 6.135923151542565e-3f;  // 2*pi/1024
    float win = 0.5f - 0.5f * cosf(CST * (float)n);
    int k = (c < CUT) ? c : (c - 512);
    int m = (k * n) & 1023;                   // exact periodic reduction
    float si, co;
    sincosf(CST * (float)m, &si, &co);
    float base = (c < CUT) ? co : -si;
    fwd[idx] = f2bf(base * win);
    float d = (c == 0 || c == 512) ? (1.0f / 1024.0f) : (2.0f / 1024.0f);
    // W[h][dd*1024 + c] = invt[n = h+256*dd][c]
    invW[((n & 255) << 12) + ((n >> 8) << 10) + c] = f2bf(0.25f * base * d * win);
}

__global__ void cvt_audio_k(const float* __restrict__ audio, ushort* __restrict__ aud) {
    int idx = blockIdx.x * blockDim.x + threadIdx.x;
    if (idx >= NB * ABLEN) return;
    int t = idx % ABLEN;
    int b = idx / ABLEN;
    float v = 0.f;
    if (t < LAUD + 1024) {
        int j = t - 512;
        if (j < 0) j = -j;
        if (j >= LAUD) j = 2 * LAUD - 2 - j;
        v = audio[(long)b * LAUD + j];
    }
    aud[idx] = f2bf(v);
}

__global__ void zero_row_k(ushort* __restrict__ ft) {
    int idx = blockIdx.x * blockDim.x + threadIdx.x;
    if (idx >= NB * 1024) return;
    int b = idx >> 10, c = idx & 1023;
    ft[(long)b * FTROWS * 1024 + c] = 0;
}

// ---- GEMM1: STFT + fused nonlin --------------------------------------------
// Flattened grid of 1056 blocks, bijectively XCD-swizzled: HW assigns block i
// to XCD i%8; we remap so XCD x gets linear work [x*132,(x+1)*132) =
// {4 c-tiles x 33 f-tiles x 1 batch} -> ~3.2 MB L2 working set per XCD.
// A-tile rows interleaved: local row r -> group g=r>>4 (even: re, odd: im).
__global__ __launch_bounds__(256) void gemm_fwd_k(
    const ushort* __restrict__ fwd, const ushort* __restrict__ aud,
    const float* __restrict__ bias, ushort* __restrict__ ft) {
    __shared__ char smem[32768];  // A 16K | B 16K
    const int tid = threadIdx.x;
    const int wid = tid >> 6, lane = tid & 63;
    const int lh = lane & 15, lg = lane >> 4;
    const int wm = wid >> 1, wn = wid & 1;
    // bijective XCD swizzle: 1056 = 8 * 132
    int w = (blockIdx.x & 7) * 132 + (blockIdx.x >> 3);
    const int f0 = (w % 33) << 7;
    const int c0 = ((w / 33) & 7) << 6;
    const int b  = w / 264;
    const ushort* ab = aud + (long)b * ABLEN;
    f32x4 acc[4][4] = {};

    for (int k0 = 0; k0 < 1024; k0 += 64) {
        if (k0) __syncthreads();
        #pragma unroll
        for (int i = 0; i < 4; ++i) {
            int ci = (i << 8) + tid;
            int row = ci >> 3;
            int ks = k0 + (((ci & 7) ^ (row & 7)) << 3);  // pre-swizzled source
            int grow = ((row >> 4) & 1) * 512 + c0 + ((row >> 5) << 4) + (row & 15);
            __builtin_amdgcn_global_load_lds(
                (const __attribute__((address_space(1))) unsigned int*)(fwd + (grow << 10) + ks),
                (__attribute__((address_space(3))) unsigned int*)(smem + (i << 12) + (wid << 10)),
                16, 0, 0);
            __builtin_amdgcn_global_load_lds(
                (const __attribute__((address_space(1))) unsigned int*)(ab + (f0 + row) * HOP + ks),
                (__attribute__((address_space(3))) unsigned int*)(smem + 16384 + (i << 12) + (wid << 10)),
                16, 0, 0);
        }
        __syncthreads();
        #pragma unroll
        for (int s = 0; s < 2; ++s) {
            bf16x8 av[4], bv[4];
            #pragma unroll
            for (int i = 0; i < 4; ++i) {
                int r = (wm << 6) + (i << 4) + lh;
                av[i] = *(const bf16x8*)(smem + (r << 7) + ((((s << 2) + lg) ^ (r & 7)) << 4));
                int q = (wn << 6) + (i << 4) + lh;
                bv[i] = *(const bf16x8*)(smem + 16384 + (q << 7) + ((((s << 2) + lg) ^ (q & 7)) << 4));
            }
            #pragma unroll
            for (int i = 0; i < 4; ++i)
                #pragma unroll
                for (int j = 0; j < 4; ++j)
                    acc[i][j] = __builtin_amdgcn_mfma_f32_16x16x32_bf16(av[i], bv[j], acc[i][j], 0, 0, 0);
        }
    }
    // fused nonlin epilogue: pairs (acc[2p], acc[2p+1]) = (re, im) rows.
    ushort* ftb = ft + (long)b * FTROWS * 1024 + 1024;  // f' = f+1
    float b512 = bias[512] * 0.1f;
    #pragma unroll
    for (int p = 0; p < 2; ++p) {
        int kbase = c0 + ((wm * 2 + p) << 4) + (lg << 2);
        float bs[4];
        #pragma unroll
        for (int q = 0; q < 4; ++q) bs[q] = bias[kbase + q] * 0.1f;
        #pragma unroll
        for (int j = 0; j < 4; ++j) {
            int f = f0 + (wn << 6) + (j << 4) + lh;
            bool valid = (f < NFR);   // frames >= NFR must be stored as ZERO
            ushort4 ore, oim;
            #pragma unroll
            for (int q = 0; q < 4; ++q) {
                float re = acc[2 * p][j][q], im = acc[2 * p + 1][j][q];
                float sre, sim;
                if (kbase + q == 0) {  // re_0 and re_512: independent lone channels
                    float mre = fabsf(re), mim = fabsf(im);
                    sre = mre > 0.f ? fmaxf(mre - bs[0], 0.f) / mre : 0.f;
                    sim = mim > 0.f ? fmaxf(mim - b512, 0.f) / mim : 0.f;
                } else {
                    float mag = sqrtf(re * re + im * im);
                    float s = mag > 0.f ? fmaxf(mag - bs[q], 0.f) / mag : 0.f;
                    sre = s; sim = s;
                }
                float vre = valid ? re * sre : 0.f;
                float vim = valid ? im * sim : 0.f;
                ((unsigned short*)&ore)[q] = f2bf(vre);
                ((unsigned short*)&oim)[q] = f2bf(vim);
            }
            *(ushort4*)(ftb + ((long)f << 10) + kbase) = ore;
            *(ushort4*)(ftb + ((long)f << 10) + 512 + kbase) = oim;
        }
    }
}

// ---- GEMM2: iSTFT + OLA folded (M=256 h, K=4096 dc, N=fo) -------------------
// 512 threads, 8 waves = 2 K-groups of 4 waves (d{0,1} | d{2,3}); combined
// through LDS. XCD-swizzled: XCD x gets 64 consecutive work items =
// {both h-tiles x 32 fo-tiles x 1 batch} -> invW + streamed ft window in L2.
__global__ __launch_bounds__(512) void gemm_ola_k(
    const ushort* __restrict__ invW, const ushort* __restrict__ ft,
    float* __restrict__ out) {
    __shared__ char smem[49152];  // group0: A 16K | B 8K ; group1 at +24576
    const int tid = threadIdx.x;
    const int wid = tid >> 6, lane = tid & 63;
    const int lh = lane & 15, lg = lane >> 4;
    const int g = wid >> 2;           // K-group
    const int wid2 = wid & 3;
    const int wm = wid2 >> 1, wn = wid2 & 1;
    const int tg = tid & 255;         // tid within group
    // bijective XCD swizzle: 512 = 8 * 64; work order: h fastest, then fo, b
    int w = (blockIdx.x & 7) * 64 + (blockIdx.x >> 3);
    const int h0  = (w & 1) << 7;
    const int fo0 = 2 + (((w >> 1) & 63) << 6);
    const int b   = w >> 7;
    const ushort* ftb = ft + (long)b * FTROWS * 1024;
    char* sm = smem + g * 24576;
    f32x4 acc[4][2] = {};

    for (int k0 = 0; k0 < 2048; k0 += 64) {
        if (k0) __syncthreads();
        int kk = (g << 11) + k0;
        int d  = kk >> 10;
        int cb = kk & 1023;
        #pragma unroll
        for (int i = 0; i < 4; ++i) {  // A: W rows h0..h0+127
            int ci = (i << 8) + tg;
            int row = ci >> 3;
            int swz = (((ci & 7) ^ (row & 7)) << 3);
            __builtin_amdgcn_global_load_lds(
                (const __attribute__((address_space(1))) unsigned int*)(invW + ((h0 + row) << 12) + kk + swz),
                (__attribute__((address_space(3))) unsigned int*)(sm + (i << 12) + (wid2 << 10)),
                16, 0, 0);
        }
        #pragma unroll
        for (int i = 0; i < 2; ++i) {  // B: rec rows fo0-d+1 .. +63
            int ci = (i << 8) + tg;
            int row = ci >> 3;
            int swz = (((ci & 7) ^ (row & 7)) << 3);
            int frow = fo0 + row - d + 1;
            __builtin_amdgcn_global_load_lds(
                (const __attribute__((address_space(1))) unsigned int*)(ftb + ((long)frow << 10) + cb + swz),
                (__attribute__((address_space(3))) unsigned int*)(sm + 16384 + (i << 12) + (wid2 << 10)),
                16, 0, 0);
        }
        __syncthreads();
        #pragma unroll
        for (int s = 0; s < 2; ++s) {
            bf16x8 av[4], bv[2];
            #pragma unroll
            for (int i = 0; i < 4; ++i) {
                int r = (wm << 6) + (i << 4) + lh;
                av[i] = *(const bf16x8*)(sm + (r << 7) + ((((s << 2) + lg) ^ (r & 7)) << 4));
            }
            #pragma unroll
            for (int j = 0; j < 2; ++j) {
                int rq = (wn << 5) + (j << 4) + lh;
                bv[j] = *(const bf16x8*)(sm + 16384 + (rq << 7) + ((((s << 2) + lg) ^ (rq & 7)) << 4));
            }
            #pragma unroll
            for (int i = 0; i < 4; ++i)
                #pragma unroll
                for (int j = 0; j < 2; ++j)
                    acc[i][j] = __builtin_amdgcn_mfma_f32_16x16x32_bf16(av[i], bv[j], acc[i][j], 0, 0, 0);
        }
    }
    // ---- combine group 1 into group 0 through LDS (32KB f32, [h][fo]) ------
    __syncthreads();
    float* red = (float*)smem;
    if (g == 1) {
        #pragma unroll
        for (int i = 0; i < 4; ++i)
            #pragma unroll
            for (int j = 0; j < 2; ++j) {
                int hl = (wm << 6) + (i << 4) + (lg << 2);
                int fl = (wn << 5) + (j << 4) + lh;
                #pragma unroll
                for (int q = 0; q < 4; ++q)
                    red[(hl + q) * 64 + fl] = acc[i][j][q];
            }
    }
    __syncthreads();
    if (g == 1) return;
    float* ob = out + (long)b * LAUD;
    const float CST = 6.135923151542565e-3f;
    #pragma unroll
    for (int i = 0; i < 4; ++i) {
        int hbase = h0 + (wm << 6) + (i << 4) + (lg << 2);
        int hl = (wm << 6) + (i << 4) + (lg << 2);
        #pragma unroll
        for (int j = 0; j < 2; ++j) {
            int fo = fo0 + (wn << 5) + (j << 4) + lh;
            int fl = (wn << 5) + (j << 4) + lh;
            f32x4 v = acc[i][j];
            #pragma unroll
            for (int q = 0; q < 4; ++q) v[q] += red[(hl + q) * 64 + fl];
            if (fo == 2 || fo == 4097) {       // partial window-sum at the edges
                #pragma unroll
                for (int q = 0; q < 4; ++q) {
                    int n = (fo == 2) ? (hbase + q + 768) : (hbase + q);
                    float w2 = 0.5f - 0.5f * cosf(CST * (float)n);
                    v[q] = v[q] * (4.0f / (1.5f - w2 * w2));
                }
            } else {
                v *= (8.0f / 3.0f);            // interior: ws == 1.5 exactly
            }
            *(f32x4*)(ob + (((long)(fo - 2)) << 8) + hbase) = v;
        }
    }
}

extern "C" void kernel_launch(void* const* d_in, const int* in_sizes, int n_in,
                              void* d_out, int out_size, void* d_ws, size_t ws_size,
                              hipStream_t stream) {
    const float* audio = (const float*)d_in[0];
    const float* bias  = (const float*)d_in[1];
    float* out = (float*)d_out;
    char* wsb = (char*)d_ws;

    ushort* fwd  = (ushort*)(wsb);
    ushort* invW = (ushort*)(wsb + 2097152);
    ushort* aud  = (ushort*)(wsb + 4194304);
    ushort* ft   = (ushort*)(wsb + 12853248);

    build_bases_k<<<4096, 256, 0, stream>>>(fwd, invW);
    cvt_audio_k<<<(NB * ABLEN + 255) / 256, 256, 0, stream>>>(audio, aud);
    zero_row_k<<<(NB * 1024 + 255) / 256, 256, 0, stream>>>(ft);

    gemm_fwd_k<<<1056, 256, 0, stream>>>(fwd, aud, bias, ft);

    gemm_ola_k<<<512, 512, 0, stream>>>(invW, ft, out);
}